// Round 7
// baseline (206.023 us; speedup 1.0000x reference)
//
#include <hip/hip_runtime.h>

// Bidirectional chamfer, B=4, N=M=5000, D=3, fp32.
// R7: single fused kernel. Each 1024-thread block stages all targets of its
// (b,dir) slice from RAW global float3 into SoA LDS (X/Y/Z/|g|^2, 80 KB),
// one barrier, then a barrier-free loop using PACKED fp32 (v_pk_fma_f32 via
// float2 vectors): 4 targets per lane per iteration from 4 ds_read_b128.
// Counter zeroed by a 4-byte hipMemsetAsync (graph-capturable).

#define BB      4
#define NP      5000
#define NPT     5120               // padded targets
#define THREADS 1024
#define WAVES   16
#define QW      10                 // queries per wave
#define QPB     (WAVES * QW)       // 160 queries per block
#define XBLKS   32                 // 32*160 = 5120 >= 5000 (masked tail)
#define GRID    (XBLKS * 2 * BB)   // 256 blocks = 1 per CU
#define KITER   (NPT / 256)        // 20: 256 targets per block-iter (4/lane)
#define BIGF    3.0e38f

typedef float v2f __attribute__((ext_vector_type(2)));

__global__ __launch_bounds__(THREADS) void dl_chamfer_kernel(
    const float* __restrict__ pred, const float* __restrict__ gt,
    float* __restrict__ partials,      // [GRID]
    unsigned* __restrict__ counter,    // zeroed via memset before launch
    float* __restrict__ out) {
    const int qblk = blockIdx.x;            // 0..31
    const int bz   = blockIdx.y;            // 0..7
    const int b    = bz >> 1;
    const int dir  = bz & 1;
    const float* qsrc = dir ? gt   : pred;
    const float* tsrc = dir ? pred : gt;

    const int lane = threadIdx.x & 63;
    const int wave = __builtin_amdgcn_readfirstlane(threadIdx.x >> 6);

    // SoA LDS: X | Y | Z | W(=|g|^2), each NPT floats. 80 KB total.
    __shared__ float buf[4 * NPT];

    // ---- stage raw target floats (coalesced reads, /3 scatter into SoA)
    const float* tb = tsrc + (size_t)b * NP * 3;
    for (int i = threadIdx.x; i < 3 * NP; i += THREADS) {
        const float v = tb[i];
        const int j = i / 3;              // magic-mul div
        const int c = i - 3 * j;
        buf[c * NPT + j] = v;
    }

    // ---- this wave's 10 queries from raw global (wave-uniform -> s_load)
    float qx[QW], qy[QW], qz[QW], q2[QW];
    v2f m01[QW], m23[QW];
    const int qbase = qblk * QPB + wave * QW;
    #pragma unroll
    for (int r = 0; r < QW; ++r) {
        const int qi = (qbase + r < NP) ? (qbase + r) : 0;
        const float* qp = qsrc + ((size_t)b * NP + qi) * 3;
        const float x = qp[0], y = qp[1], z = qp[2];
        q2[r] = x * x + y * y + z * z;
        qx[r] = -2.0f * x; qy[r] = -2.0f * y; qz[r] = -2.0f * z;
        m01[r] = (v2f){BIGF, BIGF}; m23[r] = (v2f){BIGF, BIGF};
    }
    __syncthreads();

    // ---- norms + sentinel padding
    for (int t = threadIdx.x; t < NPT; t += THREADS) {
        if (t < NP) {
            const float x = buf[t], y = buf[NPT + t], z = buf[2 * NPT + t];
            buf[3 * NPT + t] = x * x + y * y + z * z;
        } else {
            buf[t] = 0.f; buf[NPT + t] = 0.f; buf[2 * NPT + t] = 0.f;
            buf[3 * NPT + t] = BIGF;   // never wins the min
        }
    }
    __syncthreads();   // last barrier before the main loop

    // ---- barrier-free main loop: 4 ds_read_b128 -> 4 targets/lane/iter
    const float4* X4 = (const float4*)(buf);
    const float4* Y4 = (const float4*)(buf + NPT);
    const float4* Z4 = (const float4*)(buf + 2 * NPT);
    const float4* W4 = (const float4*)(buf + 3 * NPT);
    #pragma unroll 2
    for (int k = 0; k < KITER; ++k) {
        const int e = k * 64 + lane;
        const float4 xv = X4[e], yv = Y4[e], zv = Z4[e], wv = W4[e];
        const v2f x01 = {xv.x, xv.y}, x23 = {xv.z, xv.w};
        const v2f y01 = {yv.x, yv.y}, y23 = {yv.z, yv.w};
        const v2f z01 = {zv.x, zv.y}, z23 = {zv.z, zv.w};
        const v2f w01 = {wv.x, wv.y}, w23 = {wv.z, wv.w};
        #pragma unroll
        for (int r = 0; r < QW; ++r) {
            // |g|^2 - 2 q.g, two targets per packed op (v_pk_fma_f32)
            v2f d01 = z01 * qz[r] + w01;
            d01 = y01 * qy[r] + d01;
            d01 = x01 * qx[r] + d01;
            v2f d23 = z23 * qz[r] + w23;
            d23 = y23 * qy[r] + d23;
            d23 = x23 * qx[r] + d23;
            m01[r].x = fminf(m01[r].x, d01.x);
            m01[r].y = fminf(m01[r].y, d01.y);
            m23[r].x = fminf(m23[r].x, d23.x);
            m23[r].y = fminf(m23[r].y, d23.y);
        }
    }

    // ---- fold 4 partial mins, then cross-lane butterfly
    float m[QW];
    #pragma unroll
    for (int r = 0; r < QW; ++r) {
        float v = fminf(fminf(m01[r].x, m01[r].y), fminf(m23[r].x, m23[r].y));
        #pragma unroll
        for (int off = 1; off < 64; off <<= 1)
            v = fminf(v, __shfl_xor(v, off, 64));
        m[r] = v;
    }

    // ---- per-wave row sums (mask padded queries), then block sum
    __shared__ float wsum[WAVES];
    if (lane == 0) {
        float s = 0.0f;
        #pragma unroll
        for (int r = 0; r < QW; ++r) {
            const float c = fmaxf(q2[r] + m[r], 0.0f);
            s += (qbase + r < NP) ? c : 0.0f;
        }
        wsum[wave] = s;
    }
    __syncthreads();

    const int bid = blockIdx.y * XBLKS + blockIdx.x;
    __shared__ unsigned lastFlag;
    if (threadIdx.x == 0) {
        float s = 0.0f;
        #pragma unroll
        for (int w = 0; w < WAVES; ++w) s += wsum[w];
        partials[bid] = s;
        __threadfence();
        lastFlag = (atomicAdd(counter, 1u) == GRID - 1) ? 1u : 0u;
    }
    __syncthreads();

    // ---- last-block finalize: sum 256 partials
    if (lastFlag) {
        __threadfence();
        float s = 0.0f;
        for (int i = threadIdx.x; i < GRID; i += THREADS)
            s += __hip_atomic_load((const float*)partials + i, __ATOMIC_RELAXED,
                                   __HIP_MEMORY_SCOPE_AGENT);
        #pragma unroll
        for (int off = 32; off > 0; off >>= 1)
            s += __shfl_down(s, off, 64);
        if (lane == 0) wsum[wave] = s;   // reuse wsum after barrier above
        __syncthreads();
        if (threadIdx.x == 0) {
            float t = 0.0f;
            #pragma unroll
            for (int w = 0; w < WAVES; ++w) t += wsum[w];
            out[0] = t / (float)(BB * NP);
        }
    }
}

extern "C" void kernel_launch(void* const* d_in, const int* in_sizes, int n_in,
                              void* d_out, int out_size, void* d_ws, size_t ws_size,
                              hipStream_t stream) {
    const float* pred = (const float*)d_in[0];
    const float* gt   = (const float*)d_in[1];
    float* partials   = (float*)d_ws;                    // 256 floats
    unsigned* counter = (unsigned*)(partials + GRID);    // 1 u32
    float* out        = (float*)d_out;

    hipMemsetAsync(counter, 0, sizeof(unsigned), stream);  // graph-legal
    dl_chamfer_kernel<<<dim3(XBLKS, 2 * BB), THREADS, 0, stream>>>(
        pred, gt, partials, counter, out);
}